// Round 1
// baseline (933.727 us; speedup 1.0000x reference)
//
#include <hip/hip_runtime.h>

typedef __bf16 bf16x8 __attribute__((ext_vector_type(8)));
typedef float f32x4 __attribute__((ext_vector_type(4)));

#define INV_SQRT3f 0.57735026918962576f

// ---------------- kernel 0: weight prep into MFMA B-fragment layout ----------------
// For each weight W[c][w] (c = contraction, w = out col), place bf16 value at
// fragment slot: block (Wi,kt,ct) of 1KB, lane = (c&31)/8*16 + n, j = c&7.
// PERMUTED column mapping: w = 8*n + ct  (lane n holds 8 CONSECUTIVE output
// columns across the 8 ct-accumulators -> contiguous per-lane epilogue data).
__global__ void wprep_kernel(const float* __restrict__ wss,
                             const float* __restrict__ wsv,
                             const float* __restrict__ wvs,
                             const float* __restrict__ wvv,
                             unsigned short* __restrict__ wfrag) {
  int tid = blockIdx.x * 256 + threadIdx.x;  // 0..65535
  int Wi = tid >> 14;
  int idx = tid & 16383;
  int c = idx >> 7;
  int w = idx & 127;
  const float* src = (Wi == 0) ? wss : (Wi == 1) ? wsv : (Wi == 2) ? wvs : wvv;
  float v = src[idx];
  if (Wi == 3) v *= INV_SQRT3f;  // fold inv_sqrt3 into w_vv
  unsigned u = __builtin_bit_cast(unsigned, v);
  u += 0x7FFFu + ((u >> 16) & 1u);  // RNE to bf16
  int kt = c >> 5, kk = c & 31, g = kk >> 3, j = kk & 7;
  int ct = w & 7, n = w >> 3;  // PERM: col w = 8*n + ct
  wfrag[(((Wi * 4 + kt) * 8 + ct) << 9) + (g * 16 + n) * 8 + j] = (unsigned short)(u >> 16);
}

// compile-time component select (indices constant after full unroll)
__device__ __forceinline__ float fc(const float4& v, int i) {
  return (i == 0) ? v.x : (i == 1) ? v.y : (i == 2) ? v.z : v.w;
}

struct RawBuf {
  float4 fs[4][2];  // xs: per kt, 8 floats
  float4 fv[4][6];  // xv: per kt, 24 floats (8 channels x 3 comps)
  float4 yA;        // y row for A-scaling (row = R0 + li)
  float4 yE[4];     // y rows for epilogue (rows = R0 + g*4 + rr)
};

__device__ __forceinline__ void load_raw(RawBuf& r, const float* __restrict__ x,
                                         const float* __restrict__ y,
                                         int R0, int g, int li) {
  const int rowA = R0 + li;
  const float* px = x + (size_t)rowA * 512;
#pragma unroll
  for (int kt = 0; kt < 4; ++kt) {
#pragma unroll
    for (int q = 0; q < 2; ++q)
      r.fs[kt][q] = *(const float4*)(px + kt * 32 + g * 8 + q * 4);
#pragma unroll
    for (int q = 0; q < 6; ++q)
      r.fv[kt][q] = *(const float4*)(px + 128 + (kt * 32 + g * 8) * 3 + q * 4);
  }
  r.yA = *(const float4*)(y + (size_t)rowA * 4);
#pragma unroll
  for (int rr = 0; rr < 4; ++rr)
    r.yE[rr] = *(const float4*)(y + (size_t)(R0 + g * 4 + rr) * 4);
}

struct Frags {
  bf16x8 ss[4], sv[4], dd[4], v0[4], v1[4], v2[4];
};

__device__ __forceinline__ void convert(Frags& F, const RawBuf& r) {
  const float ys = r.yA.x, yv0 = r.yA.y, yv1 = r.yA.z, yv2 = r.yA.w;
#pragma unroll
  for (int kt = 0; kt < 4; ++kt) {
#pragma unroll
    for (int j = 0; j < 8; ++j) {
      float s = fc(r.fs[kt][j >> 2], j & 3);
      float a = fc(r.fv[kt][(3 * j) >> 2], (3 * j) & 3);
      float bb = fc(r.fv[kt][(3 * j + 1) >> 2], (3 * j + 1) & 3);
      float cc = fc(r.fv[kt][(3 * j + 2) >> 2], (3 * j + 2) & 3);
      F.ss[kt][j] = (__bf16)(ys * s);
      F.sv[kt][j] = (__bf16)(s);
      F.v0[kt][j] = (__bf16)(ys * a);
      F.v1[kt][j] = (__bf16)(ys * bb);
      F.v2[kt][j] = (__bf16)(ys * cc);
      F.dd[kt][j] = (__bf16)(a * yv0 + bb * yv1 + cc * yv2);
    }
  }
}

__global__ __launch_bounds__(256, 1) void fused_kernel(
    const float* __restrict__ x, const float* __restrict__ y,
    const float* __restrict__ b, const unsigned short* __restrict__ wfrag,
    float* __restrict__ out) {
  __shared__ unsigned short wlds[65536];  // 128 KB: 4 weights x 4 kt x 8 ct x 1KB frag blocks
  __shared__ float ostage[4][4][512];     // 32 KB: per-wave 4-row (2KB) output staging
  {
    const float4* s = (const float4*)wfrag;
    float4* d = (float4*)wlds;
    const int t = threadIdx.x;
#pragma unroll
    for (int i = 0; i < 32; ++i) d[t + i * 256] = s[t + i * 256];
  }
  __syncthreads();

  const int wid = threadIdx.x >> 6;
  const int lane = threadIdx.x & 63;
  const int g = lane >> 4, li = lane & 15;
  const int lofs = lane * 8;  // ushort offset of this lane's 16B frag slice

  char* const sbw = (char*)ostage[wid];  // this wave's 8KB staging region

  // bias: lane li owns cols 8*li .. 8*li+7 (permuted layout) -> contiguous load
  float breg[8];
  {
    float4 b0 = *(const float4*)(b + 8 * li);
    float4 b1 = *(const float4*)(b + 8 * li + 4);
    breg[0] = b0.x; breg[1] = b0.y; breg[2] = b0.z; breg[3] = b0.w;
    breg[4] = b1.x; breg[5] = b1.y; breg[6] = b1.z; breg[7] = b1.w;
  }

  const int rowBase = blockIdx.x * 512 + wid * 16;

  RawBuf cur;
  load_raw(cur, x, y, rowBase, g, li);

#pragma unroll 2
  for (int t = 0; t < 8; ++t) {
    const int R0 = rowBase + t * 64;
    Frags F;
    convert(F, cur);
    RawBuf nxt;
    if (t < 7) load_raw(nxt, x, y, R0 + 64, g, li);  // prefetch next group (hides HBM latency)

    f32x4 accS[8], accP[8], accQ0[8], accQ1[8], accQ2[8];
    const f32x4 zz = {0.f, 0.f, 0.f, 0.f};
#pragma unroll
    for (int ct = 0; ct < 8; ++ct) {
      accS[ct] = zz; accP[ct] = zz; accQ0[ct] = zz; accQ1[ct] = zz; accQ2[ct] = zz;
    }

#pragma unroll
    for (int kt = 0; kt < 4; ++kt) {
#pragma unroll
      for (int ct = 0; ct < 8; ++ct) {
        const bf16x8 Bss = *(const bf16x8*)&wlds[((0 * 4 + kt) * 8 + ct) * 512 + lofs];
        const bf16x8 Bsv = *(const bf16x8*)&wlds[((1 * 4 + kt) * 8 + ct) * 512 + lofs];
        const bf16x8 Bvs = *(const bf16x8*)&wlds[((2 * 4 + kt) * 8 + ct) * 512 + lofs];
        const bf16x8 Bvv = *(const bf16x8*)&wlds[((3 * 4 + kt) * 8 + ct) * 512 + lofs];
        accS[ct]  = __builtin_amdgcn_mfma_f32_16x16x32_bf16(F.ss[kt], Bss, accS[ct], 0, 0, 0);
        accS[ct]  = __builtin_amdgcn_mfma_f32_16x16x32_bf16(F.dd[kt], Bvv, accS[ct], 0, 0, 0);
        accP[ct]  = __builtin_amdgcn_mfma_f32_16x16x32_bf16(F.sv[kt], Bsv, accP[ct], 0, 0, 0);
        accQ0[ct] = __builtin_amdgcn_mfma_f32_16x16x32_bf16(F.v0[kt], Bvs, accQ0[ct], 0, 0, 0);
        accQ1[ct] = __builtin_amdgcn_mfma_f32_16x16x32_bf16(F.v1[kt], Bvs, accQ1[ct], 0, 0, 0);
        accQ2[ct] = __builtin_amdgcn_mfma_f32_16x16x32_bf16(F.v2[kt], Bvs, accQ2[ct], 0, 0, 0);
      }
    }

    // ---------------- epilogue ----------------
    // C/D layout: col = lane&15, row = (lane>>4)*4 + reg  [m89-verified]
    // Permuted cols: acc ct of lane li -> output col 8*li + ct.
    // Per rr: each group g assembles its full 2KB row (lane li holds bytes
    // [32*li,+32) of scalar seg and [96*li,+96) of vector seg), stages it in
    // LDS (XOR-swizzled on bits 4-5 -> bank-BW floor), then ALL 64 lanes
    // stream out 4 rows with dwordx4 stores covering contiguous aligned 1KB
    // per instruction -> full-line HBM writes, no partial-sector RMW.
#pragma unroll
    for (int rr = 0; rr < 4; ++rr) {
      const float4 ye = cur.yE[rr];

      f32x4 sb0, sb1;
#pragma unroll
      for (int ct = 0; ct < 4; ++ct) sb0[ct] = accS[ct][rr] + breg[ct];
#pragma unroll
      for (int ct = 0; ct < 4; ++ct) sb1[ct] = accS[ct + 4][rr] + breg[ct + 4];

      f32x4 vb[6];
#pragma unroll
      for (int ct = 0; ct < 8; ++ct) {
        const float p = accP[ct][rr];
        const float o0 = fmaf(ye.y, p, accQ0[ct][rr]);
        const float o1 = fmaf(ye.z, p, accQ1[ct][rr]);
        const float o2 = fmaf(ye.w, p, accQ2[ct][rr]);
        const int e = 3 * ct;
        vb[e >> 2][e & 3] = o0;
        vb[(e + 1) >> 2][(e + 1) & 3] = o1;
        vb[(e + 2) >> 2][(e + 2) & 3] = o2;
      }

      // stage this group's row into slot g (byte-addr XOR swizzle on bits 4-5)
      const int sx = g << 4;
      const int rb = g * 2048;
      *(f32x4*)(sbw + ((rb + 32 * li) ^ sx)) = sb0;
      *(f32x4*)(sbw + ((rb + 32 * li + 16) ^ sx)) = sb1;
#pragma unroll
      for (int q = 0; q < 6; ++q)
        *(f32x4*)(sbw + ((rb + 512 + 96 * li + 16 * q) ^ sx)) = vb[q];

      // cooperative streamout: 4 rows x 2KB; each store instr = contiguous 1KB
#pragma unroll
      for (int s = 0; s < 4; ++s) {
        const int sxs = s << 4;
        const f32x4 r0 = *(const f32x4*)(sbw + ((s * 2048 + 16 * lane) ^ sxs));
        const f32x4 r1 = *(const f32x4*)(sbw + ((s * 2048 + 1024 + 16 * lane) ^ sxs));
        char* po = (char*)(out + (size_t)(R0 + s * 4 + rr) * 512);
        *(f32x4*)(po + 16 * lane) = r0;
        *(f32x4*)(po + 1024 + 16 * lane) = r1;
      }
    }
    if (t < 7) cur = nxt;
  }
}

extern "C" void kernel_launch(void* const* d_in, const int* in_sizes, int n_in,
                              void* d_out, int out_size, void* d_ws, size_t ws_size,
                              hipStream_t stream) {
  const float* x = (const float*)d_in[0];
  const float* y = (const float*)d_in[1];
  const float* wss = (const float*)d_in[2];
  const float* wsv = (const float*)d_in[3];
  const float* wvs = (const float*)d_in[4];
  const float* wvv = (const float*)d_in[5];
  const float* b = (const float*)d_in[6];
  float* out = (float*)d_out;
  unsigned short* wfrag = (unsigned short*)d_ws;  // 128 KB used

  wprep_kernel<<<256, 256, 0, stream>>>(wss, wsv, wvs, wvv, wfrag);
  fused_kernel<<<512, 256, 0, stream>>>(x, y, b, wfrag, out);
}

// Round 2
// 763.756 us; speedup vs baseline: 1.2225x; 1.2225x over previous
//
#include <hip/hip_runtime.h>

typedef __bf16 bf16x8 __attribute__((ext_vector_type(8)));
typedef float f32x4 __attribute__((ext_vector_type(4)));

#define INV_SQRT3f 0.57735026918962576f

// ---------------- kernel 0: weight prep into MFMA B-fragment layout ----------------
// For each weight W[c][w] (c = contraction, w = out col), place bf16 value at
// fragment slot: block (Wi,kt,ct) of 1KB, lane = (c&31)/8*16 + (w&15), j = c&7.
__global__ void wprep_kernel(const float* __restrict__ wss,
                             const float* __restrict__ wsv,
                             const float* __restrict__ wvs,
                             const float* __restrict__ wvv,
                             unsigned short* __restrict__ wfrag) {
  int tid = blockIdx.x * 256 + threadIdx.x;  // 0..65535
  int Wi = tid >> 14;
  int idx = tid & 16383;
  int c = idx >> 7;
  int w = idx & 127;
  const float* src = (Wi == 0) ? wss : (Wi == 1) ? wsv : (Wi == 2) ? wvs : wvv;
  float v = src[idx];
  if (Wi == 3) v *= INV_SQRT3f;  // fold inv_sqrt3 into w_vv
  unsigned u = __builtin_bit_cast(unsigned, v);
  u += 0x7FFFu + ((u >> 16) & 1u);  // RNE to bf16
  int kt = c >> 5, kk = c & 31, g = kk >> 3, j = kk & 7;
  int ct = w >> 4, n = w & 15;
  wfrag[(((Wi * 4 + kt) * 8 + ct) << 9) + (g * 16 + n) * 8 + j] = (unsigned short)(u >> 16);
}

// compile-time component select (indices constant after full unroll)
__device__ __forceinline__ float fc(const float4& v, int i) {
  return (i == 0) ? v.x : (i == 1) ? v.y : (i == 2) ? v.z : v.w;
}

struct RawBuf {
  float4 fs[4][2];  // xs: per kt, 8 floats
  float4 fv[4][6];  // xv: per kt, 24 floats (8 channels x 3 comps)
  float4 yA;        // y row for A-scaling (row = R0 + li)
  float4 yE[4];     // y rows for epilogue (rows = R0 + g*4 + rr)
};

__device__ __forceinline__ void load_raw(RawBuf& r, const float* __restrict__ x,
                                         const float* __restrict__ y,
                                         int R0, int g, int li) {
  const int rowA = R0 + li;
  const float* px = x + (size_t)rowA * 512;
#pragma unroll
  for (int kt = 0; kt < 4; ++kt) {
#pragma unroll
    for (int q = 0; q < 2; ++q)
      r.fs[kt][q] = *(const float4*)(px + kt * 32 + g * 8 + q * 4);
#pragma unroll
    for (int q = 0; q < 6; ++q)
      r.fv[kt][q] = *(const float4*)(px + 128 + (kt * 32 + g * 8) * 3 + q * 4);
  }
  r.yA = *(const float4*)(y + (size_t)rowA * 4);
#pragma unroll
  for (int rr = 0; rr < 4; ++rr)
    r.yE[rr] = *(const float4*)(y + (size_t)(R0 + g * 4 + rr) * 4);
}

struct Frags {
  bf16x8 ss[4], sv[4], dd[4], v0[4], v1[4], v2[4];
};

// Consumes r.fs/fv/yA — after this call the raw x-data registers are DEAD.
__device__ __forceinline__ void convert(Frags& F, const RawBuf& r) {
  const float ys = r.yA.x, yv0 = r.yA.y, yv1 = r.yA.z, yv2 = r.yA.w;
#pragma unroll
  for (int kt = 0; kt < 4; ++kt) {
#pragma unroll
    for (int j = 0; j < 8; ++j) {
      float s = fc(r.fs[kt][j >> 2], j & 3);
      float a = fc(r.fv[kt][(3 * j) >> 2], (3 * j) & 3);
      float bb = fc(r.fv[kt][(3 * j + 1) >> 2], (3 * j + 1) & 3);
      float cc = fc(r.fv[kt][(3 * j + 2) >> 2], (3 * j + 2) & 3);
      F.ss[kt][j] = (__bf16)(ys * s);
      F.sv[kt][j] = (__bf16)(s);
      F.v0[kt][j] = (__bf16)(ys * a);
      F.v1[kt][j] = (__bf16)(ys * bb);
      F.v2[kt][j] = (__bf16)(ys * cc);
      F.dd[kt][j] = (__bf16)(a * yv0 + bb * yv1 + cc * yv2);
    }
  }
}

__global__ __launch_bounds__(256, 1) void fused_kernel(
    const float* __restrict__ x, const float* __restrict__ y,
    const float* __restrict__ b, const unsigned short* __restrict__ wfrag,
    float* __restrict__ out) {
  __shared__ unsigned short wlds[65536];  // 128 KB: 4 weights x 4 kt x 8 ct x 1KB frag blocks
  {
    const float4* s = (const float4*)wfrag;
    float4* d = (float4*)wlds;
    const int t = threadIdx.x;
#pragma unroll
    for (int i = 0; i < 32; ++i) d[t + i * 256] = s[t + i * 256];
  }
  __syncthreads();

  const int wid = threadIdx.x >> 6;
  const int lane = threadIdx.x & 63;
  const int g = lane >> 4, li = lane & 15;
  const int lofs = lane * 8;  // ushort offset of this lane's 16B frag slice

  float breg[8];
#pragma unroll
  for (int ct = 0; ct < 8; ++ct) breg[ct] = b[ct * 16 + li];

  const int rowBase = blockIdx.x * 512 + wid * 16;

  RawBuf cur;
  load_raw(cur, x, y, rowBase, g, li);

  Frags F;

  // t-loop: NOT unrolled (unrolling duplicates the 148-reg raw-buffer live
  // range and forces spills to scratch -> the 1+ GB of parasitic HBM traffic
  // seen in rounds 0/1).
#pragma unroll 1
  for (int t = 0; t < 8; ++t) {
    const int R0 = rowBase + t * 64;

    // Convert raw -> bf16 fragments NOW: cur.fs/fv (132 regs) die here.
    convert(F, cur);

    // Issue next group's loads early; they complete under the MFMA work.
    RawBuf nxt;
    if (t < 7) load_raw(nxt, x, y, R0 + 64, g, li);

    // Two ct-halves: accumulator live set is 5*4*4 = 80 regs instead of 160.
    // All indices compile-time (h/c4/kt fully unrolled).
#pragma unroll
    for (int h = 0; h < 2; ++h) {
      f32x4 accS[4], accP[4], accQ0[4], accQ1[4], accQ2[4];
      const f32x4 zz = {0.f, 0.f, 0.f, 0.f};
#pragma unroll
      for (int c4 = 0; c4 < 4; ++c4) {
        accS[c4] = zz; accP[c4] = zz; accQ0[c4] = zz; accQ1[c4] = zz; accQ2[c4] = zz;
      }

#pragma unroll
      for (int kt = 0; kt < 4; ++kt) {
#pragma unroll
        for (int c4 = 0; c4 < 4; ++c4) {
          const int ct = h * 4 + c4;
          const bf16x8 Bss = *(const bf16x8*)&wlds[((0 * 4 + kt) * 8 + ct) * 512 + lofs];
          const bf16x8 Bsv = *(const bf16x8*)&wlds[((1 * 4 + kt) * 8 + ct) * 512 + lofs];
          const bf16x8 Bvs = *(const bf16x8*)&wlds[((2 * 4 + kt) * 8 + ct) * 512 + lofs];
          const bf16x8 Bvv = *(const bf16x8*)&wlds[((3 * 4 + kt) * 8 + ct) * 512 + lofs];
          accS[c4]  = __builtin_amdgcn_mfma_f32_16x16x32_bf16(F.ss[kt], Bss, accS[c4], 0, 0, 0);
          accS[c4]  = __builtin_amdgcn_mfma_f32_16x16x32_bf16(F.dd[kt], Bvv, accS[c4], 0, 0, 0);
          accP[c4]  = __builtin_amdgcn_mfma_f32_16x16x32_bf16(F.sv[kt], Bsv, accP[c4], 0, 0, 0);
          accQ0[c4] = __builtin_amdgcn_mfma_f32_16x16x32_bf16(F.v0[kt], Bvs, accQ0[c4], 0, 0, 0);
          accQ1[c4] = __builtin_amdgcn_mfma_f32_16x16x32_bf16(F.v1[kt], Bvs, accQ1[c4], 0, 0, 0);
          accQ2[c4] = __builtin_amdgcn_mfma_f32_16x16x32_bf16(F.v2[kt], Bvs, accQ2[c4], 0, 0, 0);
        }
      }

      // epilogue (this half): C/D layout col = lane&15, row = (lane>>4)*4 + reg.
      // Stores are line-complete: scalar = 4x64B contiguous runs per instr,
      // float3 = 4x192B contiguous 64B-aligned runs per instr.
#pragma unroll
      for (int rr = 0; rr < 4; ++rr) {
        const int row = R0 + g * 4 + rr;
        float* po = out + (size_t)row * 512;
        const float4 ye = cur.yE[rr];
#pragma unroll
        for (int c4 = 0; c4 < 4; ++c4) {
          const int ct = h * 4 + c4;
          po[ct * 16 + li] = accS[c4][rr] + breg[ct];
          const float p = accP[c4][rr];
          const int w = ct * 16 + li;
          float3 o;
          o.x = fmaf(ye.y, p, accQ0[c4][rr]);
          o.y = fmaf(ye.z, p, accQ1[c4][rr]);
          o.z = fmaf(ye.w, p, accQ2[c4][rr]);
          *(float3*)(po + 128 + 3 * w) = o;  // 12B contiguous per lane -> dwordx3
        }
      }
    }

    if (t < 7) cur = nxt;
  }
}

extern "C" void kernel_launch(void* const* d_in, const int* in_sizes, int n_in,
                              void* d_out, int out_size, void* d_ws, size_t ws_size,
                              hipStream_t stream) {
  const float* x = (const float*)d_in[0];
  const float* y = (const float*)d_in[1];
  const float* wss = (const float*)d_in[2];
  const float* wsv = (const float*)d_in[3];
  const float* wvs = (const float*)d_in[4];
  const float* wvv = (const float*)d_in[5];
  const float* b = (const float*)d_in[6];
  float* out = (float*)d_out;
  unsigned short* wfrag = (unsigned short*)d_ws;  // 128 KB used

  wprep_kernel<<<256, 256, 0, stream>>>(wss, wsv, wvs, wvv, wfrag);
  fused_kernel<<<512, 256, 0, stream>>>(x, y, b, wfrag, out);
}

// Round 3
// 493.330 us; speedup vs baseline: 1.8927x; 1.5482x over previous
//
#include <hip/hip_runtime.h>

typedef __bf16 bf16x8 __attribute__((ext_vector_type(8)));
typedef float f32x4 __attribute__((ext_vector_type(4)));

#define INV_SQRT3f 0.57735026918962576f

// ---------------- kernel 0: weight prep into MFMA B-fragment layout ----------------
// For each weight W[c][w] (c = contraction, w = out col), place bf16 value at
// fragment slot: block (Wi,kt,ct) of 1KB, lane = (c&31)/8*16 + (w&15), j = c&7.
__global__ void wprep_kernel(const float* __restrict__ wss,
                             const float* __restrict__ wsv,
                             const float* __restrict__ wvs,
                             const float* __restrict__ wvv,
                             unsigned short* __restrict__ wfrag) {
  int tid = blockIdx.x * 256 + threadIdx.x;  // 0..65535
  int Wi = tid >> 14;
  int idx = tid & 16383;
  int c = idx >> 7;
  int w = idx & 127;
  const float* src = (Wi == 0) ? wss : (Wi == 1) ? wsv : (Wi == 2) ? wvs : wvv;
  float v = src[idx];
  if (Wi == 3) v *= INV_SQRT3f;  // fold inv_sqrt3 into w_vv
  unsigned u = __builtin_bit_cast(unsigned, v);
  u += 0x7FFFu + ((u >> 16) & 1u);  // RNE to bf16
  int kt = c >> 5, kk = c & 31, g = kk >> 3, j = kk & 7;
  int ct = w >> 4, n = w & 15;
  wfrag[(((Wi * 4 + kt) * 8 + ct) << 9) + (g * 16 + n) * 8 + j] = (unsigned short)(u >> 16);
}

// compile-time component select (indices constant after full unroll)
__device__ __forceinline__ float fc(const float4& v, int i) {
  return (i == 0) ? v.x : (i == 1) ? v.y : (i == 2) ? v.z : v.w;
}

// One kt-slice of a row's raw x data: 32 floats/lane (8 xs + 24 xv).
struct Chunk {
  float4 fs[2];
  float4 fv[6];
};

__device__ __forceinline__ void load_chunk(Chunk& c, const float* __restrict__ x,
                                           int rowA, int kt, int g) {
  const float* px = x + (size_t)rowA * 512;
#pragma unroll
  for (int q = 0; q < 2; ++q)
    c.fs[q] = *(const float4*)(px + kt * 32 + g * 8 + q * 4);
#pragma unroll
  for (int q = 0; q < 6; ++q)
    c.fv[q] = *(const float4*)(px + 128 + kt * 96 + g * 24 + q * 4);
}

// Fragments for one kt-slice. yv is folded into the A-side (sv_i = yv_i*xs),
// so the epilogue needs no y at all and accP is eliminated.
struct FragK {
  bf16x8 ss, sv0, sv1, sv2, dd, v0, v1, v2;
};

__device__ __forceinline__ void convert_chunk(FragK& F, const Chunk& c, const float4 yA) {
  const float ys = yA.x, yv0 = yA.y, yv1 = yA.z, yv2 = yA.w;
#pragma unroll
  for (int j = 0; j < 8; ++j) {
    float s = fc(c.fs[j >> 2], j & 3);
    float a = fc(c.fv[(3 * j) >> 2], (3 * j) & 3);
    float bb = fc(c.fv[(3 * j + 1) >> 2], (3 * j + 1) & 3);
    float cc = fc(c.fv[(3 * j + 2) >> 2], (3 * j + 2) & 3);
    F.ss[j] = (__bf16)(ys * s);
    F.sv0[j] = (__bf16)(yv0 * s);
    F.sv1[j] = (__bf16)(yv1 * s);
    F.sv2[j] = (__bf16)(yv2 * s);
    F.v0[j] = (__bf16)(ys * a);
    F.v1[j] = (__bf16)(ys * bb);
    F.v2[j] = (__bf16)(ys * cc);
    F.dd[j] = (__bf16)fmaf(a, yv0, fmaf(bb, yv1, cc * yv2));
  }
}

__device__ __forceinline__ void mfma_chunk(f32x4 (&accS)[8], f32x4 (&accV0)[8],
                                           f32x4 (&accV1)[8], f32x4 (&accV2)[8],
                                           const FragK& F, int kt,
                                           const unsigned short* wlds, int lofs) {
#pragma unroll
  for (int ct = 0; ct < 8; ++ct) {
    const bf16x8 Bss = *(const bf16x8*)&wlds[((0 * 4 + kt) * 8 + ct) * 512 + lofs];
    const bf16x8 Bsv = *(const bf16x8*)&wlds[((1 * 4 + kt) * 8 + ct) * 512 + lofs];
    const bf16x8 Bvs = *(const bf16x8*)&wlds[((2 * 4 + kt) * 8 + ct) * 512 + lofs];
    const bf16x8 Bvv = *(const bf16x8*)&wlds[((3 * 4 + kt) * 8 + ct) * 512 + lofs];
    accS[ct] = __builtin_amdgcn_mfma_f32_16x16x32_bf16(F.ss, Bss, accS[ct], 0, 0, 0);
    accS[ct] = __builtin_amdgcn_mfma_f32_16x16x32_bf16(F.dd, Bvv, accS[ct], 0, 0, 0);
    accV0[ct] = __builtin_amdgcn_mfma_f32_16x16x32_bf16(F.sv0, Bsv, accV0[ct], 0, 0, 0);
    accV0[ct] = __builtin_amdgcn_mfma_f32_16x16x32_bf16(F.v0, Bvs, accV0[ct], 0, 0, 0);
    accV1[ct] = __builtin_amdgcn_mfma_f32_16x16x32_bf16(F.sv1, Bsv, accV1[ct], 0, 0, 0);
    accV1[ct] = __builtin_amdgcn_mfma_f32_16x16x32_bf16(F.v1, Bvs, accV1[ct], 0, 0, 0);
    accV2[ct] = __builtin_amdgcn_mfma_f32_16x16x32_bf16(F.sv2, Bsv, accV2[ct], 0, 0, 0);
    accV2[ct] = __builtin_amdgcn_mfma_f32_16x16x32_bf16(F.v2, Bvs, accV2[ct], 0, 0, 0);
  }
}

__global__ __launch_bounds__(256, 1) void fused_kernel(
    const float* __restrict__ x, const float* __restrict__ y,
    const float* __restrict__ b, const unsigned short* __restrict__ wfrag,
    float* __restrict__ out) {
  __shared__ unsigned short wlds[65536];  // 128 KB: 4 weights x 4 kt x 8 ct x 1KB frag blocks
  {
    const float4* s = (const float4*)wfrag;
    float4* d = (float4*)wlds;
    const int t = threadIdx.x;
#pragma unroll
    for (int i = 0; i < 32; ++i) d[t + i * 256] = s[t + i * 256];
  }
  __syncthreads();

  const int wid = threadIdx.x >> 6;
  const int lane = threadIdx.x & 63;
  const int g = lane >> 4, li = lane & 15;
  const int lofs = lane * 8;  // ushort offset of this lane's 16B frag slice

  float breg[8];
#pragma unroll
  for (int ct = 0; ct < 8; ++ct) breg[ct] = b[ct * 16 + li];

  const int rowBase = blockIdx.x * 512 + wid * 16;
  const int rA0 = rowBase + li;

  // Pipeline prologue: two kt-chunks in flight (prefetch distance 2).
  Chunk C0, C1;
  load_chunk(C0, x, rA0, 0, g);
  load_chunk(C1, x, rA0, 1, g);
  float4 yAc = *(const float4*)(y + (size_t)rA0 * 4);

  // t-loop NOT unrolled: loop-carried state is only C0+C1 (64 regs) + yAc.
  // Raw data converts to bf16 frags per-chunk and dies immediately -> peak
  // live set ~265 regs, fits the 512-wide unified VGPR/AGPR file at 1 wave/SIMD
  // with zero scratch (the rounds-0..2 kernels spilled a 148-reg loop-carried
  // buffer to scratch every iteration: ~1 GB of parasitic HBM traffic).
#pragma unroll 1
  for (int t = 0; t < 8; ++t) {
    const int R0 = rowBase + t * 64;
    const int rowA = R0 + li;
    const int rowN = rowA + 64;

    f32x4 accS[8], accV0[8], accV1[8], accV2[8];
    const f32x4 zz = {0.f, 0.f, 0.f, 0.f};
#pragma unroll
    for (int ct = 0; ct < 8; ++ct) {
      accS[ct] = zz; accV0[ct] = zz; accV1[ct] = zz; accV2[ct] = zz;
    }

    float4 yAn;

    // ---- chunk kt=0 (buffer C0) ----
    {
      FragK F;
      convert_chunk(F, C0, yAc);           // C0 raw regs die here
      load_chunk(C0, x, rowA, 2, g);       // issue (t, kt=2)
      mfma_chunk(accS, accV0, accV1, accV2, F, 0, wlds, lofs);
    }
    // ---- chunk kt=1 (buffer C1) ----
    {
      FragK F;
      convert_chunk(F, C1, yAc);
      load_chunk(C1, x, rowA, 3, g);       // issue (t, kt=3)
      mfma_chunk(accS, accV0, accV1, accV2, F, 1, wlds, lofs);
    }
    // ---- chunk kt=2 (buffer C0) ----
    {
      FragK F;
      convert_chunk(F, C0, yAc);
      if (t < 7) load_chunk(C0, x, rowN, 0, g);  // issue (t+1, kt=0)
      mfma_chunk(accS, accV0, accV1, accV2, F, 2, wlds, lofs);
    }
    // ---- chunk kt=3 (buffer C1) ----
    {
      FragK F;
      convert_chunk(F, C1, yAc);
      if (t < 7) {
        load_chunk(C1, x, rowN, 1, g);     // issue (t+1, kt=1)
        yAn = *(const float4*)(y + (size_t)rowN * 4);
      }
      mfma_chunk(accS, accV0, accV1, accV2, F, 3, wlds, lofs);
    }

    // epilogue: C/D layout col = lane&15, row = (lane>>4)*4 + reg [m89-verified].
    // No y needed (yv folded into A-frags). Stores are line-complete:
    // scalar = 4x64B contiguous runs/instr, float3 = 4x192B contiguous
    // 64B-aligned runs/instr.
#pragma unroll
    for (int rr = 0; rr < 4; ++rr) {
      const int row = R0 + g * 4 + rr;
      float* po = out + (size_t)row * 512;
#pragma unroll
      for (int ct = 0; ct < 8; ++ct) {
        po[ct * 16 + li] = accS[ct][rr] + breg[ct];
        const int w = ct * 16 + li;
        float3 o;
        o.x = accV0[ct][rr];
        o.y = accV1[ct][rr];
        o.z = accV2[ct][rr];
        *(float3*)(po + 128 + 3 * w) = o;  // 12B contiguous per lane -> dwordx3
      }
    }

    if (t < 7) yAc = yAn;
  }
}

extern "C" void kernel_launch(void* const* d_in, const int* in_sizes, int n_in,
                              void* d_out, int out_size, void* d_ws, size_t ws_size,
                              hipStream_t stream) {
  const float* x = (const float*)d_in[0];
  const float* y = (const float*)d_in[1];
  const float* wss = (const float*)d_in[2];
  const float* wsv = (const float*)d_in[3];
  const float* wvs = (const float*)d_in[4];
  const float* wvv = (const float*)d_in[5];
  const float* b = (const float*)d_in[6];
  float* out = (float*)d_out;
  unsigned short* wfrag = (unsigned short*)d_ws;  // 128 KB used

  wprep_kernel<<<256, 256, 0, stream>>>(wss, wsv, wvs, wvv, wfrag);
  fused_kernel<<<512, 256, 0, stream>>>(x, y, b, wfrag, out);
}